// Round 9
// baseline (423.537 us; speedup 1.0000x reference)
//
#include <hip/hip_runtime.h>
#include <hip/hip_fp16.h>
#include <math.h>

#define N_NODES 100000
#define D_FEAT  128
#define E_EDGES 1600000
#define E2      (E_EDGES + N_NODES)   /* 1,700,000 with self-loops */
#define NEG_SLOPE 0.2f
#define LN_EPS    1e-5f

#define NB   391                      /* buckets of 256 nodes: d >> 8 */
#define TS   8192                     /* edges per tile */
#define NTIL ((E2 + TS - 1) / TS)     /* 208 */

typedef __attribute__((ext_vector_type(4))) float floatx4;
typedef _Float16 h2 __attribute__((ext_vector_type(2)));   // packed half pair
typedef _Float16 h8 __attribute__((ext_vector_type(8)));   // fp16 MFMA fragment

static __device__ __forceinline__ float fdot2f(h2 a, h2 b, float c) {
#if __has_builtin(__builtin_amdgcn_fdot2)
    return __builtin_amdgcn_fdot2(a, b, c, false);
#else
    return (float)a[0] * (float)b[0] + (float)a[1] * (float)b[1] + c;
#endif
}

static __device__ __forceinline__ h2 shfl_xor_h2(h2 v, int off) {
    int i = __builtin_bit_cast(int, v);
    i = __shfl_xor(i, off);
    return __builtin_bit_cast(h2, i);
}

// ---------------------------------------------------------------------------
// CSR build v12 (unchanged): radix with LDS atomics + rank-reuse.
// ---------------------------------------------------------------------------
__global__ __launch_bounds__(1024) void tile_count(const int* __restrict__ edge_dst,
                                                   int* __restrict__ tcnt,
                                                   unsigned short* __restrict__ rankbuf) {
    __shared__ int h[NB];
    const int t = threadIdx.x;
    if (t < NB) h[t] = 0;
    __syncthreads();
    const int base = blockIdx.x * TS;
#pragma unroll
    for (int j = 0; j < TS / 1024; ++j) {
        int i = base + j * 1024 + t;
        if (i < E2) {
            int d = (i < E_EDGES) ? edge_dst[i] : (i - E_EDGES);
            int rk = atomicAdd(&h[d >> 8], 1);
            rankbuf[i] = (unsigned short)rk;      // rank within (tile,bucket)
        }
    }
    __syncthreads();
    if (t < NB) tcnt[blockIdx.x * NB + t] = h[t];
}

__global__ __launch_bounds__(256) void col_scan(const int* __restrict__ tcnt,
                                                int* __restrict__ toff,
                                                int* __restrict__ bcnt) {
    __shared__ int s[256];
    const int b = blockIdx.x;
    const int t = threadIdx.x;
    int v = (t < NTIL) ? tcnt[t * NB + b] : 0;
    s[t] = v;
    __syncthreads();
    for (int off = 1; off < 256; off <<= 1) {
        int x = (t >= off) ? s[t - off] : 0;
        __syncthreads();
        s[t] += x;
        __syncthreads();
    }
    if (t < NTIL) toff[t * NB + b] = s[t] - v;   // exclusive
    if (t == 255) bcnt[b] = s[255];
}

__global__ __launch_bounds__(512) void bucket_scan(const int* __restrict__ bcnt,
                                                   int* __restrict__ bstart,
                                                   int* __restrict__ rowstart) {
    __shared__ int s[512];
    const int t = threadIdx.x;
    int v = (t < NB) ? bcnt[t] : 0;
    s[t] = v;
    __syncthreads();
    for (int off = 1; off < 512; off <<= 1) {
        int x = (t >= off) ? s[t - off] : 0;
        __syncthreads();
        s[t] += x;
        __syncthreads();
    }
    if (t <= NB) bstart[t] = s[t] - v;   // t==NB: total == E2
    if (t == 0) rowstart[N_NODES] = E2;
}

__global__ __launch_bounds__(1024) void tile_scatter(const int* __restrict__ edge_src,
                                                     const int* __restrict__ edge_dst,
                                                     const int* __restrict__ bstart,
                                                     const int* __restrict__ toff,
                                                     const unsigned short* __restrict__ rankbuf,
                                                     unsigned* __restrict__ pairbuf) {
    __shared__ int base[NB];
    const int t = threadIdx.x;
    if (t < NB) base[t] = bstart[t] + toff[blockIdx.x * NB + t];
    __syncthreads();
    const int tb = blockIdx.x * TS;
#pragma unroll
    for (int j = 0; j < TS / 1024; ++j) {
        int i = tb + j * 1024 + t;
        if (i < E2) {
            int d, sr;
            if (i < E_EDGES) { d = edge_dst[i]; sr = edge_src[i]; }
            else             { d = i - E_EDGES; sr = d; }
            int b = d >> 8;
            int pos = base[b] + (int)rankbuf[i];            // no atomics
            pairbuf[pos] = (unsigned)sr | ((unsigned)(d & 255) << 17);
        }
    }
}

__global__ __launch_bounds__(1024) void bucketize(const unsigned* __restrict__ pairbuf,
                                                  const int* __restrict__ bstart,
                                                  int* __restrict__ rowstart,
                                                  int* __restrict__ csr_src) {
    __shared__ int cnt[256], off[256];
    const int blk = blockIdx.x;
    const int t = threadIdx.x;
    const int nbase = blk << 8;
    if (t < 256) cnt[t] = 0;
    __syncthreads();
    const int e0 = bstart[blk], e1 = bstart[blk + 1];

    // stage up to 8 edges per thread (max bucket ~4700 << 8192 capacity)
    unsigned pr0, pr1, pr2, pr3, pr4, pr5, pr6, pr7;
    int rk0, rk1, rk2, rk3, rk4, rk5, rk6, rk7;
#define LOADP(K, PR)  { int p = e0 + t + (K) * 1024; PR = (p < e1) ? pairbuf[p] : 0u; }
    LOADP(0, pr0) LOADP(1, pr1) LOADP(2, pr2) LOADP(3, pr3)
    LOADP(4, pr4) LOADP(5, pr5) LOADP(6, pr6) LOADP(7, pr7)
#undef LOADP
#define HIST(K, PR, RK) { int p = e0 + t + (K) * 1024; \
        RK = (p < e1) ? atomicAdd(&cnt[PR >> 17], 1) : 0; }
    HIST(0, pr0, rk0) HIST(1, pr1, rk1) HIST(2, pr2, rk2) HIST(3, pr3, rk3)
    HIST(4, pr4, rk4) HIST(5, pr5, rk5) HIST(6, pr6, rk6) HIST(7, pr7, rk7)
#undef HIST
    __syncthreads();

    // exclusive scan of the 256 per-node counts
    int v = (t < 256) ? cnt[t] : 0;
    __shared__ int sc[256];
    if (t < 256) sc[t] = v;
    __syncthreads();
    for (int o = 1; o < 256; o <<= 1) {
        int x = (t < 256 && t >= o) ? sc[t - o] : 0;
        __syncthreads();
        if (t < 256) sc[t] += x;
        __syncthreads();
    }
    if (t < 256) {
        int excl = sc[t] - v;
        int node = nbase + t;
        if (node < N_NODES) rowstart[node] = e0 + excl;
        off[t] = e0 + excl;
    }
    __syncthreads();

    // direct scatter using register-held (pair, rank)
#define SCAT(K, PR, RK) { int p = e0 + t + (K) * 1024; \
        if (p < e1) csr_src[off[PR >> 17] + RK] = (int)(PR & 0x1FFFF); }
    SCAT(0, pr0, rk0) SCAT(1, pr1, rk1) SCAT(2, pr2, rk2) SCAT(3, pr3, rk3)
    SCAT(4, pr4, rk4) SCAT(5, pr5, rk5) SCAT(6, pr6, rk6) SCAT(7, pr7, rk7)
#undef SCAT
}

// ---------------------------------------------------------------------------
// Weight prep: Wt[l][side][col][k] fp16 from W[l][k][col] fp32, att -> fp16.
// ---------------------------------------------------------------------------
__global__ void prep_wt(const float* __restrict__ Wl, const float* __restrict__ Wr,
                        const float* __restrict__ att,
                        _Float16* __restrict__ Wt, _Float16* __restrict__ atth) {
    int idx = blockIdx.x * 256 + threadIdx.x;
    if (idx < 65536) {                       // 2 layers * 2 sides * 128*128
        int l    = idx >> 15;
        int rem  = idx & 32767;
        int side = rem >> 14;
        int cw   = rem & 16383;
        int col  = cw >> 7, k = cw & 127;
        const float* W = side ? Wr : Wl;
        Wt[idx] = (_Float16)W[l * 16384 + k * 128 + col];
    } else if (idx < 65536 + 256) {
        int j = idx - 65536;
        atth[j] = (_Float16)att[j];
    }
}

// ---------------------------------------------------------------------------
// MFMA GEMM v13: wave = 16 rows x 256 cols (was 32x256).
// Grid 782 -> 1563 blocks = 6.1 waves/SIMD (was 3.05): the gemm was
// latency-bound at 3 waves/SIMD with no LDS staging; double the TLP.
// Per-wave: 64 MFMA, 16 acc VGPRs, one A fragment.
// ---------------------------------------------------------------------------
__global__ __launch_bounds__(256) void gemm_mfma4(
        const _Float16* __restrict__ hA,          // fp16 N x 128 (layer 1) or null
        const float* __restrict__ Afp,            // fp32 N x 128 (layer 0) or null
        const _Float16* __restrict__ Wt,          // fp16 [2][128][128] this layer
        _Float16* __restrict__ xl, _Float16* __restrict__ xr, int n_rows) {
    const int wave = threadIdx.x >> 6;
    const int lane = threadIdx.x & 63;
    const int m = lane & 15;
    const int q = lane >> 4;
    const int r0 = (blockIdx.x * 4 + wave) * 16;

    int arow = r0 + m;   if (arow >= n_rows) arow = n_rows - 1;

    floatx4 acc[2][8];      // [side][ct]
#pragma unroll
    for (int s = 0; s < 2; ++s)
#pragma unroll
        for (int ct = 0; ct < 8; ++ct) acc[s][ct] = (floatx4){0.f,0.f,0.f,0.f};

#pragma unroll
    for (int ks = 0; ks < 4; ++ks) {
        const int k0 = ks * 32 + q * 8;
        h8 a0;
        if (Afp) {
            float4 f0 = *(const float4*)(Afp + (size_t)arow * 128 + k0);
            float4 f1 = *(const float4*)(Afp + (size_t)arow * 128 + k0 + 4);
            a0 = (h8){(_Float16)f0.x, (_Float16)f0.y, (_Float16)f0.z, (_Float16)f0.w,
                      (_Float16)f1.x, (_Float16)f1.y, (_Float16)f1.z, (_Float16)f1.w};
        } else {
            a0 = *(const h8*)(hA + (size_t)arow * 128 + k0);
        }
#pragma unroll
        for (int s = 0; s < 2; ++s) {
#pragma unroll
            for (int ct = 0; ct < 8; ++ct) {
                h8 b = *(const h8*)(Wt + (size_t)s * 16384
                                    + (size_t)(ct * 16 + m) * 128 + k0);
                acc[s][ct] = __builtin_amdgcn_mfma_f32_16x16x32_f16(a0, b, acc[s][ct], 0, 0, 0);
            }
        }
    }

#pragma unroll
    for (int s = 0; s < 2; ++s) {
        _Float16* out = s ? xr : xl;
#pragma unroll
        for (int ct = 0; ct < 8; ++ct)
#pragma unroll
            for (int i = 0; i < 4; ++i) {
                int row = r0 + q * 4 + i;
                if (row < n_rows)
                    out[(size_t)row * 128 + ct * 16 + m] = (_Float16)acc[s][ct][i];
            }
    }
}

// ---------------------------------------------------------------------------
// Fused per-node GATv2 (v10 structure, unchanged): zero LDS, 3-slot pipeline,
// shfl-butterfly epilogue, fp16 residual path between layers.
// ---------------------------------------------------------------------------
union U16 { uint4 u; h2 h[4]; };

__global__ __launch_bounds__(256) void gat_node10(
        const _Float16* __restrict__ xl,          // fp16 N x 128
        const _Float16* __restrict__ xr,          // fp16 N x 128
        const float* __restrict__ h_in_f32,       // layer 0: x, else null
        const _Float16* __restrict__ h_in_f16,    // layer 1: h16, else null
        const int* __restrict__ rowstart, const int* __restrict__ csr_src,
        const _Float16* __restrict__ atth, const float* __restrict__ bias,
        const float* __restrict__ gamma, const float* __restrict__ beta,
        float* __restrict__ out_f32,              // layer 1 output, else null
        _Float16* __restrict__ out_f16) {         // layer 0 output, else null
    const int wave = threadIdx.x >> 6;
    const int lane = threadIdx.x & 63;
    const int node = blockIdx.x * 4 + wave;       // grid exact: 25000*4
    const int esub = lane >> 3;
    const int r    = lane & 7;
    const int c0   = r * 16;
    const int c    = c0 + 2 * esub;               // output channel pair

    const int p0 = rowstart[node], p1 = rowstart[node + 1];
    const int pe = p1 - 1;                        // deg >= 1 (self-loop)

    U16 xra, xrb, ata, atb;
    {
        const uint4* xp = (const uint4*)(xr + (size_t)node * 128 + c0);
        xra.u = xp[0]; xrb.u = xp[1];
        const uint4* ap = (const uint4*)(atth + c0);
        ata.u = ap[0]; atb.u = ap[1];
    }
    const float2 bi = *(const float2*)(bias + c); // epilogue const, hoisted
    const h2 ns2 = {(_Float16)NEG_SLOPE, (_Float16)NEG_SLOPE};

    const unsigned short* xls = (const unsigned short*)xl;

    float s = 0.f;
    h2 acc2[8];
#pragma unroll
    for (int j = 0; j < 8; ++j) acc2[j] = (h2){(_Float16)0.f, (_Float16)0.f};

    // dot + weighted accumulate for one 8-edge batch (two indep FMA chains)
    auto consume = [&](const U16& u0, const U16& u1, bool v) {
        float da = 0.f, db = 0.f;
#pragma unroll
        for (int qq = 0; qq < 4; ++qq) {
            h2 z  = u0.h[qq] + xra.h[qq];
            h2 lk = __builtin_elementwise_max(z, z * ns2);
            da = fdot2f(lk, ata.h[qq], da);
        }
#pragma unroll
        for (int qq = 0; qq < 4; ++qq) {
            h2 z  = u1.h[qq] + xrb.h[qq];
            h2 lk = __builtin_elementwise_max(z, z * ns2);
            db = fdot2f(lk, atb.h[qq], db);
        }
        float d = da + db;
        float alpha = d + __shfl_xor(d, 1);        // half-head pair -> head dot
        float w = v ? __expf(alpha) : 0.f;
        s += w;
        h2 w2 = {(_Float16)w, (_Float16)w};
#pragma unroll
        for (int qq = 0; qq < 4; ++qq)
            acc2[qq] = w2 * u0.h[qq] + acc2[qq];
#pragma unroll
        for (int qq = 0; qq < 4; ++qq)
            acc2[qq + 4] = w2 * u1.h[qq] + acc2[qq + 4];
    };

    // ---- prologue: indices for batches 0,1,2; gathers for batches 0,1 ----
    int pA = p0 + esub;        if (pA > pe) pA = pe;
    int pB = p0 + 8 + esub;    if (pB > pe) pB = pe;
    int pC = p0 + 16 + esub;   if (pC > pe) pC = pe;
    int i0 = csr_src[pA];
    int i1 = csr_src[pB];
    int i2 = csr_src[pC];

    U16 s0a, s0b, s1a, s1b, s2a, s2b;
    { const uint4* rp = (const uint4*)(xls + (size_t)i0 * 128 + c0); s0a.u = rp[0]; s0b.u = rp[1]; }
    { const uint4* rp = (const uint4*)(xls + (size_t)i1 * 128 + c0); s1a.u = rp[0]; s1b.u = rp[1]; }

    int pb = p0;
    for (;;) {
        // ---- body 0: csr t+3 -> i0; gather t+2 via i2 -> slot2; consume slot0
        {
            int pn = pb + 24 + esub; if (pn > pe) pn = pe;
            int inew = csr_src[pn];                         // batch t+3 index
            if (pb + 16 < p1) {                             // wave-uniform
                const uint4* rp = (const uint4*)(xls + (size_t)i2 * 128 + c0);
                s2a.u = rp[0]; s2b.u = rp[1];
            }
            consume(s0a, s0b, (pb + esub) < p1);
            i0 = inew;
            pb += 8; if (pb >= p1) break;
        }
        // ---- body 1: csr t+3 -> i1; gather t+2 via i0 -> slot0; consume slot1
        {
            int pn = pb + 24 + esub; if (pn > pe) pn = pe;
            int inew = csr_src[pn];
            if (pb + 16 < p1) {
                const uint4* rp = (const uint4*)(xls + (size_t)i0 * 128 + c0);
                s0a.u = rp[0]; s0b.u = rp[1];
            }
            consume(s1a, s1b, (pb + esub) < p1);
            i1 = inew;
            pb += 8; if (pb >= p1) break;
        }
        // ---- body 2: csr t+3 -> i2; gather t+2 via i1 -> slot1; consume slot2
        {
            int pn = pb + 24 + esub; if (pn > pe) pn = pe;
            int inew = csr_src[pn];
            if (pb + 16 < p1) {
                const uint4* rp = (const uint4*)(xls + (size_t)i1 * 128 + c0);
                s1a.u = rp[0]; s1b.u = rp[1];
            }
            consume(s2a, s2b, (pb + esub) < p1);
            i2 = inew;
            pb += 8; if (pb >= p1) break;
        }
    }

    // ---- per-head softmax denominator: sum s across esub lanes ----
    float ssum = s;
    ssum += __shfl_xor(ssum, 8);
    ssum += __shfl_xor(ssum, 16);
    ssum += __shfl_xor(ssum, 32);
    // every lane now holds S for head (r>>1) == head of its output channels

    // ---- cross-esub butterfly reduction of acc2 (recursive halving) ----
    const bool sel0 = (esub & 1) != 0;
    const bool sel1 = ((esub >> 1) & 1) != 0;
    const bool sel2 = ((esub >> 2) & 1) != 0;
    h2 b4[4];
#pragma unroll
    for (int k = 0; k < 4; ++k) {
        h2 keep = sel0 ? acc2[2 * k + 1] : acc2[2 * k];
        h2 send = sel0 ? acc2[2 * k]     : acc2[2 * k + 1];
        b4[k] = keep + shfl_xor_h2(send, 8);
    }
    h2 c2[2];
#pragma unroll
    for (int k = 0; k < 2; ++k) {
        h2 keep = sel1 ? b4[2 * k + 1] : b4[2 * k];
        h2 send = sel1 ? b4[2 * k]     : b4[2 * k + 1];
        c2[k] = keep + shfl_xor_h2(send, 16);
    }
    h2 keepf = sel2 ? c2[1] : c2[0];
    h2 sendf = sel2 ? c2[0] : c2[1];
    h2 tot = keepf + shfl_xor_h2(sendf, 32);
    // tot = channels (c, c+1) summed over all 8 edge slots

    const float invS = 1.f / ssum;
    float g0 = (float)tot[0] * invS + bi.x;
    float g1 = (float)tot[1] * invS + bi.y;

    // issue remaining epilogue loads before the LN allreduce (latency cover)
    const float2 ga = *(const float2*)(gamma + c);
    const float2 be = *(const float2*)(beta + c);
    float hx, hy;
    if (h_in_f16) {
        h2 hv = *(const h2*)(h_in_f16 + (size_t)node * 128 + c);
        hx = (float)hv[0]; hy = (float)hv[1];
    } else {
        float2 hv = *(const float2*)(h_in_f32 + (size_t)node * 128 + c);
        hx = hv.x; hy = hv.y;
    }

    // ---- LayerNorm over 128 channels (full-wave allreduce) ----
    float sum = g0 + g1, sq = g0 * g0 + g1 * g1;
#pragma unroll
    for (int off = 1; off < 64; off <<= 1) {
        sum += __shfl_xor(sum, off);
        sq  += __shfl_xor(sq, off);
    }
    float mu   = sum * (1.f / 128.f);
    float var  = sq * (1.f / 128.f) - mu * mu;
    float rstd = rsqrtf(var + LN_EPS);
    float y0 = (g0 - mu) * rstd * ga.x + be.x;
    float y1 = (g1 - mu) * rstd * ga.y + be.y;
    float e0 = (y0 > 0.f) ? y0 : (__expf(y0) - 1.f);
    float e1 = (y1 > 0.f) ? y1 : (__expf(y1) - 1.f);

    float ox = hx + e0;
    float oy = hy + e1;
    if (out_f32) {
        float2 o; o.x = ox; o.y = oy;
        *(float2*)(out_f32 + (size_t)node * 128 + c) = o;
    } else {
        h2 po = {(_Float16)ox, (_Float16)oy};
        *(h2*)(out_f16 + (size_t)node * 128 + c) = po;
    }
}

// ---------------------------------------------------------------------------
extern "C" void kernel_launch(void* const* d_in, const int* in_sizes, int n_in,
                              void* d_out, int out_size, void* d_ws, size_t ws_size,
                              hipStream_t stream) {
    const float* x     = (const float*)d_in[0];
    const int*   eidx  = (const int*)d_in[1];   // (2, E)
    const float* Wl    = (const float*)d_in[2]; // (L,128,128)
    const float* Wr    = (const float*)d_in[3];
    const float* att   = (const float*)d_in[4]; // (L,4,32) -> stride 128
    const float* bias  = (const float*)d_in[5];
    const float* gamma = (const float*)d_in[6];
    const float* beta  = (const float*)d_in[7];
    float* out = (float*)d_out;

    char* ws = (char*)d_ws;
    _Float16* xl = (_Float16*)ws;              ws += (size_t)N_NODES * 128 * 2;
    _Float16* xr = (_Float16*)ws;              ws += (size_t)N_NODES * 128 * 2;
    _Float16* h16 = (_Float16*)ws;             ws += (size_t)N_NODES * 128 * 2;
    _Float16* Wt  = (_Float16*)ws;             ws += (size_t)65536 * 2;
    _Float16* atth = (_Float16*)ws;            ws += 256 * 2;
    unsigned* pairbuf = (unsigned*)ws;         ws += (size_t)E2 * 4;
    unsigned short* rankbuf = (unsigned short*)ws; ws += (size_t)E2 * 2;
    int* tcnt     = (int*)ws; ws += (size_t)NTIL * NB * 4;
    int* toff     = (int*)ws; ws += (size_t)NTIL * NB * 4;
    int* bcnt     = (int*)ws; ws += (NB + 1) * 4;
    int* bstart   = (int*)ws; ws += (NB + 1) * 4;
    int* rowstart = (int*)ws; ws += (size_t)(N_NODES + 4) * 4;
    int* csr_src  = (int*)ws; ws += (size_t)E2 * 4;

    const int* edge_src = eidx;
    const int* edge_dst = eidx + E_EDGES;

    // ---- prep: weights -> transposed fp16, att -> fp16 ----
    prep_wt<<<257, 256, 0, stream>>>(Wl, Wr, att, Wt, atth);

    // ---- CSR build (radix, rank-reuse) ----
    tile_count<<<NTIL, 1024, 0, stream>>>(edge_dst, tcnt, rankbuf);
    col_scan<<<NB, 256, 0, stream>>>(tcnt, toff, bcnt);
    bucket_scan<<<1, 512, 0, stream>>>(bcnt, bstart, rowstart);
    tile_scatter<<<NTIL, 1024, 0, stream>>>(edge_src, edge_dst, bstart, toff,
                                            rankbuf, pairbuf);
    bucketize<<<NB, 1024, 0, stream>>>(pairbuf, bstart, rowstart, csr_src);

    // ---- two GATv2 layers (fp16 intermediate h16 between them) ----
    const int gemm_gx = (N_NODES + 63) / 64;     // 1563: 16 rows/wave, 4 waves/blk
    for (int l = 0; l < 2; ++l) {
        gemm_mfma4<<<gemm_gx, 256, 0, stream>>>(
            (l == 0) ? nullptr : h16, (l == 0) ? x : nullptr,
            Wt + (size_t)l * 32768, xl, xr, N_NODES);
        gat_node10<<<N_NODES / 4, 256, 0, stream>>>(
            xl, xr,
            (l == 0) ? x : nullptr, (l == 0) ? nullptr : h16,
            rowstart, csr_src,
            atth + l * 128, bias + l * 128, gamma + l * 128, beta + l * 128,
            (l == 1) ? out : nullptr, (l == 0) ? h16 : nullptr);
    }
}

// Round 10
// 364.658 us; speedup vs baseline: 1.1615x; 1.1615x over previous
//
#include <hip/hip_runtime.h>
#include <hip/hip_fp16.h>
#include <math.h>

#define N_NODES 100000
#define D_FEAT  128
#define E_EDGES 1600000
#define E2      (E_EDGES + N_NODES)   /* 1,700,000 with self-loops */
#define NEG_SLOPE 0.2f
#define LN_EPS    1e-5f

#define NB   391                      /* buckets of 256 nodes: d >> 8 */
#define TS   8192                     /* edges per tile */
#define NTIL ((E2 + TS - 1) / TS)     /* 208 */

typedef __attribute__((ext_vector_type(4))) float floatx4;
typedef _Float16 h2 __attribute__((ext_vector_type(2)));   // packed half pair
typedef _Float16 h8 __attribute__((ext_vector_type(8)));   // fp16 MFMA fragment

static __device__ __forceinline__ float fdot2f(h2 a, h2 b, float c) {
#if __has_builtin(__builtin_amdgcn_fdot2)
    return __builtin_amdgcn_fdot2(a, b, c, false);
#else
    return (float)a[0] * (float)b[0] + (float)a[1] * (float)b[1] + c;
#endif
}

static __device__ __forceinline__ h2 shfl_xor_h2(h2 v, int off) {
    int i = __builtin_bit_cast(int, v);
    i = __shfl_xor(i, off);
    return __builtin_bit_cast(h2, i);
}

// ---------------------------------------------------------------------------
// CSR build v12 (unchanged): radix with LDS atomics + rank-reuse.
// ---------------------------------------------------------------------------
__global__ __launch_bounds__(1024) void tile_count(const int* __restrict__ edge_dst,
                                                   int* __restrict__ tcnt,
                                                   unsigned short* __restrict__ rankbuf) {
    __shared__ int h[NB];
    const int t = threadIdx.x;
    if (t < NB) h[t] = 0;
    __syncthreads();
    const int base = blockIdx.x * TS;
#pragma unroll
    for (int j = 0; j < TS / 1024; ++j) {
        int i = base + j * 1024 + t;
        if (i < E2) {
            int d = (i < E_EDGES) ? edge_dst[i] : (i - E_EDGES);
            int rk = atomicAdd(&h[d >> 8], 1);
            rankbuf[i] = (unsigned short)rk;      // rank within (tile,bucket)
        }
    }
    __syncthreads();
    if (t < NB) tcnt[blockIdx.x * NB + t] = h[t];
}

__global__ __launch_bounds__(256) void col_scan(const int* __restrict__ tcnt,
                                                int* __restrict__ toff,
                                                int* __restrict__ bcnt) {
    __shared__ int s[256];
    const int b = blockIdx.x;
    const int t = threadIdx.x;
    int v = (t < NTIL) ? tcnt[t * NB + b] : 0;
    s[t] = v;
    __syncthreads();
    for (int off = 1; off < 256; off <<= 1) {
        int x = (t >= off) ? s[t - off] : 0;
        __syncthreads();
        s[t] += x;
        __syncthreads();
    }
    if (t < NTIL) toff[t * NB + b] = s[t] - v;   // exclusive
    if (t == 255) bcnt[b] = s[255];
}

__global__ __launch_bounds__(512) void bucket_scan(const int* __restrict__ bcnt,
                                                   int* __restrict__ bstart,
                                                   int* __restrict__ rowstart) {
    __shared__ int s[512];
    const int t = threadIdx.x;
    int v = (t < NB) ? bcnt[t] : 0;
    s[t] = v;
    __syncthreads();
    for (int off = 1; off < 512; off <<= 1) {
        int x = (t >= off) ? s[t - off] : 0;
        __syncthreads();
        s[t] += x;
        __syncthreads();
    }
    if (t <= NB) bstart[t] = s[t] - v;   // t==NB: total == E2
    if (t == 0) rowstart[N_NODES] = E2;
}

__global__ __launch_bounds__(1024) void tile_scatter(const int* __restrict__ edge_src,
                                                     const int* __restrict__ edge_dst,
                                                     const int* __restrict__ bstart,
                                                     const int* __restrict__ toff,
                                                     const unsigned short* __restrict__ rankbuf,
                                                     unsigned* __restrict__ pairbuf) {
    __shared__ int base[NB];
    const int t = threadIdx.x;
    if (t < NB) base[t] = bstart[t] + toff[blockIdx.x * NB + t];
    __syncthreads();
    const int tb = blockIdx.x * TS;
#pragma unroll
    for (int j = 0; j < TS / 1024; ++j) {
        int i = tb + j * 1024 + t;
        if (i < E2) {
            int d, sr;
            if (i < E_EDGES) { d = edge_dst[i]; sr = edge_src[i]; }
            else             { d = i - E_EDGES; sr = d; }
            int b = d >> 8;
            int pos = base[b] + (int)rankbuf[i];            // no atomics
            pairbuf[pos] = (unsigned)sr | ((unsigned)(d & 255) << 17);
        }
    }
}

__global__ __launch_bounds__(1024) void bucketize(const unsigned* __restrict__ pairbuf,
                                                  const int* __restrict__ bstart,
                                                  int* __restrict__ rowstart,
                                                  int* __restrict__ csr_src) {
    __shared__ int cnt[256], off[256];
    const int blk = blockIdx.x;
    const int t = threadIdx.x;
    const int nbase = blk << 8;
    if (t < 256) cnt[t] = 0;
    __syncthreads();
    const int e0 = bstart[blk], e1 = bstart[blk + 1];

    // stage up to 8 edges per thread (max bucket ~4700 << 8192 capacity)
    unsigned pr0, pr1, pr2, pr3, pr4, pr5, pr6, pr7;
    int rk0, rk1, rk2, rk3, rk4, rk5, rk6, rk7;
#define LOADP(K, PR)  { int p = e0 + t + (K) * 1024; PR = (p < e1) ? pairbuf[p] : 0u; }
    LOADP(0, pr0) LOADP(1, pr1) LOADP(2, pr2) LOADP(3, pr3)
    LOADP(4, pr4) LOADP(5, pr5) LOADP(6, pr6) LOADP(7, pr7)
#undef LOADP
#define HIST(K, PR, RK) { int p = e0 + t + (K) * 1024; \
        RK = (p < e1) ? atomicAdd(&cnt[PR >> 17], 1) : 0; }
    HIST(0, pr0, rk0) HIST(1, pr1, rk1) HIST(2, pr2, rk2) HIST(3, pr3, rk3)
    HIST(4, pr4, rk4) HIST(5, pr5, rk5) HIST(6, pr6, rk6) HIST(7, pr7, rk7)
#undef HIST
    __syncthreads();

    // exclusive scan of the 256 per-node counts
    int v = (t < 256) ? cnt[t] : 0;
    __shared__ int sc[256];
    if (t < 256) sc[t] = v;
    __syncthreads();
    for (int o = 1; o < 256; o <<= 1) {
        int x = (t < 256 && t >= o) ? sc[t - o] : 0;
        __syncthreads();
        if (t < 256) sc[t] += x;
        __syncthreads();
    }
    if (t < 256) {
        int excl = sc[t] - v;
        int node = nbase + t;
        if (node < N_NODES) rowstart[node] = e0 + excl;
        off[t] = e0 + excl;
    }
    __syncthreads();

    // direct scatter using register-held (pair, rank)
#define SCAT(K, PR, RK) { int p = e0 + t + (K) * 1024; \
        if (p < e1) csr_src[off[PR >> 17] + RK] = (int)(PR & 0x1FFFF); }
    SCAT(0, pr0, rk0) SCAT(1, pr1, rk1) SCAT(2, pr2, rk2) SCAT(3, pr3, rk3)
    SCAT(4, pr4, rk4) SCAT(5, pr5, rk5) SCAT(6, pr6, rk6) SCAT(7, pr7, rk7)
#undef SCAT
}

// ---------------------------------------------------------------------------
// Weight prep: Wt[l][side][col][k] fp16 from W[l][k][col] fp32, att -> fp16.
// ---------------------------------------------------------------------------
__global__ void prep_wt(const float* __restrict__ Wl, const float* __restrict__ Wr,
                        const float* __restrict__ att,
                        _Float16* __restrict__ Wt, _Float16* __restrict__ atth) {
    int idx = blockIdx.x * 256 + threadIdx.x;
    if (idx < 65536) {                       // 2 layers * 2 sides * 128*128
        int l    = idx >> 15;
        int rem  = idx & 32767;
        int side = rem >> 14;
        int cw   = rem & 16383;
        int col  = cw >> 7, k = cw & 127;
        const float* W = side ? Wr : Wl;
        Wt[idx] = (_Float16)W[l * 16384 + k * 128 + col];
    } else if (idx < 65536 + 256) {
        int j = idx - 65536;
        atth[j] = (_Float16)att[j];
    }
}

// ---------------------------------------------------------------------------
// MFMA GEMM v14: v12's 32-row wave geometry + Wt staged in LDS.
// v13 evidence: doubling per-row B-traffic cost +16us/layer -> gemm is bound
// on the B-operand stream (each wave read the whole 64KB panel from L2).
// Now: block stages the 64KB panel ONCE (XOR-swizzled, T2: byte^=(row&7)<<4,
// same involution write+read -> uniform 8 lanes/16B-slot = conflict-free),
// B-fragments come from ds_read_b128.
// ---------------------------------------------------------------------------
__global__ __launch_bounds__(256) void gemm_mfma5(
        const _Float16* __restrict__ hA,          // fp16 N x 128 (layer 1) or null
        const float* __restrict__ Afp,            // fp32 N x 128 (layer 0) or null
        const _Float16* __restrict__ Wt,          // fp16 [2][128][128] this layer
        _Float16* __restrict__ xl, _Float16* __restrict__ xr, int n_rows) {
    __shared__ char bsm[65536];                   // 256 rows x 256 B (exactly 64 KB)
    const int tid  = threadIdx.x;
    const int wave = tid >> 6;
    const int lane = tid & 63;
    const int m = lane & 15;
    const int q = lane >> 4;
    const int r0 = (blockIdx.x * 4 + wave) * 32;

    // ---- stage Wt panel -> LDS with XOR swizzle (16 chunks of 16B per thread)
#pragma unroll
    for (int k = 0; k < 16; ++k) {
        int ci  = tid + k * 256;                  // chunk index in [0, 4096)
        int row = ci >> 4;
        int off = (ci & 15) << 4;                 // byte offset within row
        uint4 v = *(const uint4*)((const char*)Wt + row * 256 + off);
        *(uint4*)(bsm + row * 256 + (off ^ ((row & 7) << 4))) = v;
    }
    __syncthreads();

    int arow0 = r0 + m;        if (arow0 >= n_rows) arow0 = n_rows - 1;
    int arow1 = r0 + 16 + m;   if (arow1 >= n_rows) arow1 = n_rows - 1;

    floatx4 acc[2][2][8];      // [side][rt][ct]
#pragma unroll
    for (int s = 0; s < 2; ++s)
#pragma unroll
        for (int rt = 0; rt < 2; ++rt)
#pragma unroll
            for (int ct = 0; ct < 8; ++ct) acc[s][rt][ct] = (floatx4){0.f,0.f,0.f,0.f};

    const int swz = (m & 7) << 4;                 // row&7 == m&7 (rows = ct*16+m)
#pragma unroll
    for (int ks = 0; ks < 4; ++ks) {
        const int k0 = ks * 32 + q * 8;
        const int cb = k0 * 2;                    // column byte offset
        h8 a0, a1;
        if (Afp) {
            float4 f0 = *(const float4*)(Afp + (size_t)arow0 * 128 + k0);
            float4 f1 = *(const float4*)(Afp + (size_t)arow0 * 128 + k0 + 4);
            float4 g0 = *(const float4*)(Afp + (size_t)arow1 * 128 + k0);
            float4 g1 = *(const float4*)(Afp + (size_t)arow1 * 128 + k0 + 4);
            a0 = (h8){(_Float16)f0.x, (_Float16)f0.y, (_Float16)f0.z, (_Float16)f0.w,
                      (_Float16)f1.x, (_Float16)f1.y, (_Float16)f1.z, (_Float16)f1.w};
            a1 = (h8){(_Float16)g0.x, (_Float16)g0.y, (_Float16)g0.z, (_Float16)g0.w,
                      (_Float16)g1.x, (_Float16)g1.y, (_Float16)g1.z, (_Float16)g1.w};
        } else {
            a0 = *(const h8*)(hA + (size_t)arow0 * 128 + k0);
            a1 = *(const h8*)(hA + (size_t)arow1 * 128 + k0);
        }
#pragma unroll
        for (int s = 0; s < 2; ++s) {
#pragma unroll
            for (int ct = 0; ct < 8; ++ct) {
                int row = s * 128 + ct * 16 + m;
                h8 b = *(const h8*)(bsm + row * 256 + (cb ^ swz));
                acc[s][0][ct] = __builtin_amdgcn_mfma_f32_16x16x32_f16(a0, b, acc[s][0][ct], 0, 0, 0);
                acc[s][1][ct] = __builtin_amdgcn_mfma_f32_16x16x32_f16(a1, b, acc[s][1][ct], 0, 0, 0);
            }
        }
    }

#pragma unroll
    for (int s = 0; s < 2; ++s) {
        _Float16* out = s ? xr : xl;
#pragma unroll
        for (int rt = 0; rt < 2; ++rt)
#pragma unroll
            for (int ct = 0; ct < 8; ++ct)
#pragma unroll
                for (int i = 0; i < 4; ++i) {
                    int row = r0 + rt * 16 + q * 4 + i;
                    if (row < n_rows)
                        out[(size_t)row * 128 + ct * 16 + m] = (_Float16)acc[s][rt][ct][i];
                }
    }
}

// ---------------------------------------------------------------------------
// Fused per-node GATv2 (v10 structure, unchanged): zero LDS, 3-slot pipeline,
// shfl-butterfly epilogue, fp16 residual path between layers.
// ---------------------------------------------------------------------------
union U16 { uint4 u; h2 h[4]; };

__global__ __launch_bounds__(256) void gat_node10(
        const _Float16* __restrict__ xl,          // fp16 N x 128
        const _Float16* __restrict__ xr,          // fp16 N x 128
        const float* __restrict__ h_in_f32,       // layer 0: x, else null
        const _Float16* __restrict__ h_in_f16,    // layer 1: h16, else null
        const int* __restrict__ rowstart, const int* __restrict__ csr_src,
        const _Float16* __restrict__ atth, const float* __restrict__ bias,
        const float* __restrict__ gamma, const float* __restrict__ beta,
        float* __restrict__ out_f32,              // layer 1 output, else null
        _Float16* __restrict__ out_f16) {         // layer 0 output, else null
    const int wave = threadIdx.x >> 6;
    const int lane = threadIdx.x & 63;
    const int node = blockIdx.x * 4 + wave;       // grid exact: 25000*4
    const int esub = lane >> 3;
    const int r    = lane & 7;
    const int c0   = r * 16;
    const int c    = c0 + 2 * esub;               // output channel pair

    const int p0 = rowstart[node], p1 = rowstart[node + 1];
    const int pe = p1 - 1;                        // deg >= 1 (self-loop)

    U16 xra, xrb, ata, atb;
    {
        const uint4* xp = (const uint4*)(xr + (size_t)node * 128 + c0);
        xra.u = xp[0]; xrb.u = xp[1];
        const uint4* ap = (const uint4*)(atth + c0);
        ata.u = ap[0]; atb.u = ap[1];
    }
    const float2 bi = *(const float2*)(bias + c); // epilogue const, hoisted
    const h2 ns2 = {(_Float16)NEG_SLOPE, (_Float16)NEG_SLOPE};

    const unsigned short* xls = (const unsigned short*)xl;

    float s = 0.f;
    h2 acc2[8];
#pragma unroll
    for (int j = 0; j < 8; ++j) acc2[j] = (h2){(_Float16)0.f, (_Float16)0.f};

    // dot + weighted accumulate for one 8-edge batch (two indep FMA chains)
    auto consume = [&](const U16& u0, const U16& u1, bool v) {
        float da = 0.f, db = 0.f;
#pragma unroll
        for (int qq = 0; qq < 4; ++qq) {
            h2 z  = u0.h[qq] + xra.h[qq];
            h2 lk = __builtin_elementwise_max(z, z * ns2);
            da = fdot2f(lk, ata.h[qq], da);
        }
#pragma unroll
        for (int qq = 0; qq < 4; ++qq) {
            h2 z  = u1.h[qq] + xrb.h[qq];
            h2 lk = __builtin_elementwise_max(z, z * ns2);
            db = fdot2f(lk, atb.h[qq], db);
        }
        float d = da + db;
        float alpha = d + __shfl_xor(d, 1);        // half-head pair -> head dot
        float w = v ? __expf(alpha) : 0.f;
        s += w;
        h2 w2 = {(_Float16)w, (_Float16)w};
#pragma unroll
        for (int qq = 0; qq < 4; ++qq)
            acc2[qq] = w2 * u0.h[qq] + acc2[qq];
#pragma unroll
        for (int qq = 0; qq < 4; ++qq)
            acc2[qq + 4] = w2 * u1.h[qq] + acc2[qq + 4];
    };

    // ---- prologue: indices for batches 0,1,2; gathers for batches 0,1 ----
    int pA = p0 + esub;        if (pA > pe) pA = pe;
    int pB = p0 + 8 + esub;    if (pB > pe) pB = pe;
    int pC = p0 + 16 + esub;   if (pC > pe) pC = pe;
    int i0 = csr_src[pA];
    int i1 = csr_src[pB];
    int i2 = csr_src[pC];

    U16 s0a, s0b, s1a, s1b, s2a, s2b;
    { const uint4* rp = (const uint4*)(xls + (size_t)i0 * 128 + c0); s0a.u = rp[0]; s0b.u = rp[1]; }
    { const uint4* rp = (const uint4*)(xls + (size_t)i1 * 128 + c0); s1a.u = rp[0]; s1b.u = rp[1]; }

    int pb = p0;
    for (;;) {
        // ---- body 0: csr t+3 -> i0; gather t+2 via i2 -> slot2; consume slot0
        {
            int pn = pb + 24 + esub; if (pn > pe) pn = pe;
            int inew = csr_src[pn];                         // batch t+3 index
            if (pb + 16 < p1) {                             // wave-uniform
                const uint4* rp = (const uint4*)(xls + (size_t)i2 * 128 + c0);
                s2a.u = rp[0]; s2b.u = rp[1];
            }
            consume(s0a, s0b, (pb + esub) < p1);
            i0 = inew;
            pb += 8; if (pb >= p1) break;
        }
        // ---- body 1: csr t+3 -> i1; gather t+2 via i0 -> slot0; consume slot1
        {
            int pn = pb + 24 + esub; if (pn > pe) pn = pe;
            int inew = csr_src[pn];
            if (pb + 16 < p1) {
                const uint4* rp = (const uint4*)(xls + (size_t)i0 * 128 + c0);
                s0a.u = rp[0]; s0b.u = rp[1];
            }
            consume(s1a, s1b, (pb + esub) < p1);
            i1 = inew;
            pb += 8; if (pb >= p1) break;
        }
        // ---- body 2: csr t+3 -> i2; gather t+2 via i1 -> slot1; consume slot2
        {
            int pn = pb + 24 + esub; if (pn > pe) pn = pe;
            int inew = csr_src[pn];
            if (pb + 16 < p1) {
                const uint4* rp = (const uint4*)(xls + (size_t)i1 * 128 + c0);
                s1a.u = rp[0]; s1b.u = rp[1];
            }
            consume(s2a, s2b, (pb + esub) < p1);
            i2 = inew;
            pb += 8; if (pb >= p1) break;
        }
    }

    // ---- per-head softmax denominator: sum s across esub lanes ----
    float ssum = s;
    ssum += __shfl_xor(ssum, 8);
    ssum += __shfl_xor(ssum, 16);
    ssum += __shfl_xor(ssum, 32);
    // every lane now holds S for head (r>>1) == head of its output channels

    // ---- cross-esub butterfly reduction of acc2 (recursive halving) ----
    const bool sel0 = (esub & 1) != 0;
    const bool sel1 = ((esub >> 1) & 1) != 0;
    const bool sel2 = ((esub >> 2) & 1) != 0;
    h2 b4[4];
#pragma unroll
    for (int k = 0; k < 4; ++k) {
        h2 keep = sel0 ? acc2[2 * k + 1] : acc2[2 * k];
        h2 send = sel0 ? acc2[2 * k]     : acc2[2 * k + 1];
        b4[k] = keep + shfl_xor_h2(send, 8);
    }
    h2 c2[2];
#pragma unroll
    for (int k = 0; k < 2; ++k) {
        h2 keep = sel1 ? b4[2 * k + 1] : b4[2 * k];
        h2 send = sel1 ? b4[2 * k]     : b4[2 * k + 1];
        c2[k] = keep + shfl_xor_h2(send, 16);
    }
    h2 keepf = sel2 ? c2[1] : c2[0];
    h2 sendf = sel2 ? c2[0] : c2[1];
    h2 tot = keepf + shfl_xor_h2(sendf, 32);
    // tot = channels (c, c+1) summed over all 8 edge slots

    const float invS = 1.f / ssum;
    float g0 = (float)tot[0] * invS + bi.x;
    float g1 = (float)tot[1] * invS + bi.y;

    // issue remaining epilogue loads before the LN allreduce (latency cover)
    const float2 ga = *(const float2*)(gamma + c);
    const float2 be = *(const float2*)(beta + c);
    float hx, hy;
    if (h_in_f16) {
        h2 hv = *(const h2*)(h_in_f16 + (size_t)node * 128 + c);
        hx = (float)hv[0]; hy = (float)hv[1];
    } else {
        float2 hv = *(const float2*)(h_in_f32 + (size_t)node * 128 + c);
        hx = hv.x; hy = hv.y;
    }

    // ---- LayerNorm over 128 channels (full-wave allreduce) ----
    float sum = g0 + g1, sq = g0 * g0 + g1 * g1;
#pragma unroll
    for (int off = 1; off < 64; off <<= 1) {
        sum += __shfl_xor(sum, off);
        sq  += __shfl_xor(sq, off);
    }
    float mu   = sum * (1.f / 128.f);
    float var  = sq * (1.f / 128.f) - mu * mu;
    float rstd = rsqrtf(var + LN_EPS);
    float y0 = (g0 - mu) * rstd * ga.x + be.x;
    float y1 = (g1 - mu) * rstd * ga.y + be.y;
    float e0 = (y0 > 0.f) ? y0 : (__expf(y0) - 1.f);
    float e1 = (y1 > 0.f) ? y1 : (__expf(y1) - 1.f);

    float ox = hx + e0;
    float oy = hy + e1;
    if (out_f32) {
        float2 o; o.x = ox; o.y = oy;
        *(float2*)(out_f32 + (size_t)node * 128 + c) = o;
    } else {
        h2 po = {(_Float16)ox, (_Float16)oy};
        *(h2*)(out_f16 + (size_t)node * 128 + c) = po;
    }
}

// ---------------------------------------------------------------------------
extern "C" void kernel_launch(void* const* d_in, const int* in_sizes, int n_in,
                              void* d_out, int out_size, void* d_ws, size_t ws_size,
                              hipStream_t stream) {
    const float* x     = (const float*)d_in[0];
    const int*   eidx  = (const int*)d_in[1];   // (2, E)
    const float* Wl    = (const float*)d_in[2]; // (L,128,128)
    const float* Wr    = (const float*)d_in[3];
    const float* att   = (const float*)d_in[4]; // (L,4,32) -> stride 128
    const float* bias  = (const float*)d_in[5];
    const float* gamma = (const float*)d_in[6];
    const float* beta  = (const float*)d_in[7];
    float* out = (float*)d_out;

    char* ws = (char*)d_ws;
    _Float16* xl = (_Float16*)ws;              ws += (size_t)N_NODES * 128 * 2;
    _Float16* xr = (_Float16*)ws;              ws += (size_t)N_NODES * 128 * 2;
    _Float16* h16 = (_Float16*)ws;             ws += (size_t)N_NODES * 128 * 2;
    _Float16* Wt  = (_Float16*)ws;             ws += (size_t)65536 * 2;
    _Float16* atth = (_Float16*)ws;            ws += 256 * 2;
    unsigned* pairbuf = (unsigned*)ws;         ws += (size_t)E2 * 4;
    unsigned short* rankbuf = (unsigned short*)ws; ws += (size_t)E2 * 2;
    int* tcnt     = (int*)ws; ws += (size_t)NTIL * NB * 4;
    int* toff     = (int*)ws; ws += (size_t)NTIL * NB * 4;
    int* bcnt     = (int*)ws; ws += (NB + 1) * 4;
    int* bstart   = (int*)ws; ws += (NB + 1) * 4;
    int* rowstart = (int*)ws; ws += (size_t)(N_NODES + 4) * 4;
    int* csr_src  = (int*)ws; ws += (size_t)E2 * 4;

    const int* edge_src = eidx;
    const int* edge_dst = eidx + E_EDGES;

    // ---- prep: weights -> transposed fp16, att -> fp16 ----
    prep_wt<<<257, 256, 0, stream>>>(Wl, Wr, att, Wt, atth);

    // ---- CSR build (radix, rank-reuse) ----
    tile_count<<<NTIL, 1024, 0, stream>>>(edge_dst, tcnt, rankbuf);
    col_scan<<<NB, 256, 0, stream>>>(tcnt, toff, bcnt);
    bucket_scan<<<1, 512, 0, stream>>>(bcnt, bstart, rowstart);
    tile_scatter<<<NTIL, 1024, 0, stream>>>(edge_src, edge_dst, bstart, toff,
                                            rankbuf, pairbuf);
    bucketize<<<NB, 1024, 0, stream>>>(pairbuf, bstart, rowstart, csr_src);

    // ---- two GATv2 layers (fp16 intermediate h16 between them) ----
    const int gemm_gx = (N_NODES + 127) / 128;   // 782: 32 rows/wave, 4 waves/blk
    for (int l = 0; l < 2; ++l) {
        gemm_mfma5<<<gemm_gx, 256, 0, stream>>>(
            (l == 0) ? nullptr : h16, (l == 0) ? x : nullptr,
            Wt + (size_t)l * 32768, xl, xr, N_NODES);
        gat_node10<<<N_NODES / 4, 256, 0, stream>>>(
            xl, xr,
            (l == 0) ? x : nullptr, (l == 0) ? nullptr : h16,
            rowstart, csr_src,
            atth + l * 128, bias + l * 128, gamma + l * 128, beta + l * 128,
            (l == 1) ? out : nullptr, (l == 0) ? h16 : nullptr);
    }
}